// Round 8
// baseline (121.672 us; speedup 1.0000x reference)
//
#include <hip/hip_runtime.h>
#include <math.h>

#define K_CB    32768
#define C_DIM   32
#define N_TOK   4096
#define OUT_N   (N_TOK * C_DIM)

#define SLICES  64
#define KPERSL  (K_CB / SLICES)    // 512 codes per slice
#define GROUPS  (KPERSL / 16)      // 32 groups of 16 codes
#define SCALE   4096.0f            // 2^12 pre-scale (exact)

typedef _Float16 half8   __attribute__((ext_vector_type(8)));
typedef float    floatx4 __attribute__((ext_vector_type(4)));

// ---------------------------------------------------------------------------
// Kernel A (fused prep): blocks 0..127 convert codebook -> fp16 hi/lo + norms;
// blocks 128..143 convert z -> token-major fp16 hi/lo. Zeroes the loss cell.
// ---------------------------------------------------------------------------
__global__ __launch_bounds__(256) void vq_prep(const float* __restrict__ z,
                                               const float* __restrict__ cb,
                                               _Float16* __restrict__ zh,
                                               _Float16* __restrict__ zl,
                                               _Float16* __restrict__ ch,
                                               _Float16* __restrict__ cl,
                                               float* __restrict__ nrm,
                                               float* __restrict__ out) {
    const int bb = blockIdx.x;
    if (bb < 128) {                       // ---- codebook part
        const int k = bb * 256 + threadIdx.x;
        const float4* src = (const float4*)(cb + (size_t)k * C_DIM);
        _Float16 h[C_DIM], l[C_DIM];
        float s = 0.f;
#pragma unroll
        for (int i = 0; i < 8; ++i) {
            float4 v = src[i];
            s = fmaf(v.x, v.x, s); s = fmaf(v.y, v.y, s);
            s = fmaf(v.z, v.z, s); s = fmaf(v.w, v.w, s);
            float x[4] = {v.x * SCALE, v.y * SCALE, v.z * SCALE, v.w * SCALE};
#pragma unroll
            for (int j = 0; j < 4; ++j) {
                _Float16 hh = (_Float16)x[j];
                h[i * 4 + j] = hh;
                l[i * 4 + j] = (_Float16)(x[j] - (float)hh);
            }
        }
        nrm[k] = s;
        half8* dh = (half8*)(ch + (size_t)k * C_DIM);
        half8* dl = (half8*)(cl + (size_t)k * C_DIM);
#pragma unroll
        for (int i = 0; i < 4; ++i) {
            dh[i] = *(half8*)&h[i * 8];
            dl[i] = *(half8*)&l[i * 8];
        }
        if (k == 0) out[OUT_N] = 0.f;
    } else {                              // ---- z part
        const int tok = (bb - 128) * 256 + threadIdx.x;
        const int b = tok >> 10, hw = tok & 1023;
        const float* zp = z + (size_t)b * (C_DIM * 1024) + hw;
        _Float16 h[C_DIM], l[C_DIM];
#pragma unroll
        for (int c = 0; c < C_DIM; ++c) {
            float xs = zp[(size_t)c * 1024] * SCALE;   // coalesced across lanes
            _Float16 hh = (_Float16)xs;
            h[c] = hh;
            l[c] = (_Float16)(xs - (float)hh);
        }
        half8* dh = (half8*)(zh + (size_t)tok * C_DIM);
        half8* dl = (half8*)(zl + (size_t)tok * C_DIM);
#pragma unroll
        for (int i = 0; i < 4; ++i) {
            dh[i] = *(half8*)&h[i * 8];
            dl[i] = *(half8*)&l[i * 8];
        }
    }
}

// ---------------------------------------------------------------------------
// Kernel B: MFMA argmin.  Wave = 4 strips x 16 tokens (64 tok), block = 4
// waves = 256 tokens; slice = 512 codes; grid = 16 tiles x 64 slices = 1024.
// B-fragments amortize over 4 strips (L1 traffic halved vs R7 -> MFMA-bound).
// acc = z.e*2^24 - nrm*2^23 via 3 fp16 MFMAs per strip; argmin d == argmax acc.
// Result merged globally via one u64 atomicMin per (token,slice):
// key = sortable(d)<<32 | k  (exact: min d, tie -> min k = first occurrence).
// ---------------------------------------------------------------------------
__global__ __launch_bounds__(256) void vq_mfma(const _Float16* __restrict__ zh,
                                               const _Float16* __restrict__ zl,
                                               const _Float16* __restrict__ ch,
                                               const _Float16* __restrict__ cl,
                                               const float* __restrict__ nrm,
                                               unsigned long long* __restrict__ keys) {
    const int tid   = threadIdx.x;
    const int lane  = tid & 63, wid = tid >> 6;
    const int row16 = lane & 15, kgrp = lane >> 4;
    const int tile  = blockIdx.x & 15;    // token tile (256 tokens)
    const int slice = blockIdx.x >> 4;    // code slice (512 codes)
    const int tokA  = tile * 256 + wid * 64 + row16;
    const int code0 = slice * KPERSL;

    // A fragments: 4 strips x (hi,lo), held in registers all kernel
    half8 ah[4], al[4];
#pragma unroll
    for (int s = 0; s < 4; ++s) {
        ah[s] = *(const half8*)(zh + (size_t)(tokA + s * 16) * C_DIM + kgrp * 8);
        al[s] = *(const half8*)(zl + (size_t)(tokA + s * 16) * C_DIM + kgrp * 8);
    }

    const _Float16* pbh = ch + (size_t)(code0 + row16) * C_DIM + kgrp * 8;
    const _Float16* pbl = cl + (size_t)(code0 + row16) * C_DIM + kgrp * 8;
    const float*    pn  = nrm + code0 + row16;
    int kc = code0 + row16;               // this lane's code column id

    float best[4][4]; int bk[4][4];
#pragma unroll
    for (int s = 0; s < 4; ++s)
#pragma unroll
        for (int j = 0; j < 4; ++j) { best[s][j] = -INFINITY; bk[s][j] = 0; }

    for (int g = 0; g < GROUPS; ++g) {
        half8 bh = *(const half8*)pbh;    // 16 codes hi (coalesced 1KB/wave)
        half8 bl = *(const half8*)pbl;
        float initv = (*pn) * -8388608.0f;   // -nrm/2 * 2^24
        floatx4 acc[4];
#pragma unroll
        for (int s = 0; s < 4; ++s) {     // 4 independent MFMA chains (ILP)
            acc[s] = (floatx4){initv, initv, initv, initv};
            acc[s] = __builtin_amdgcn_mfma_f32_16x16x32_f16(ah[s], bl, acc[s], 0, 0, 0);
            acc[s] = __builtin_amdgcn_mfma_f32_16x16x32_f16(al[s], bh, acc[s], 0, 0, 0);
            acc[s] = __builtin_amdgcn_mfma_f32_16x16x32_f16(ah[s], bh, acc[s], 0, 0, 0);
        }
#pragma unroll
        for (int s = 0; s < 4; ++s)
#pragma unroll
            for (int j = 0; j < 4; ++j) { // strict > keeps lowest k on in-lane ties
                float v = acc[s][j];
                bool gt = v > best[s][j];
                best[s][j] = gt ? v : best[s][j];
                bk[s][j]   = gt ? kc : bk[s][j];
            }
        pbh += 16 * C_DIM; pbl += 16 * C_DIM; pn += 16; kc += 16;
    }

    // reduce across the 16 code columns (low 4 lane bits); (max acc, min k)
#pragma unroll
    for (int off = 1; off < 16; off <<= 1)
#pragma unroll
        for (int s = 0; s < 4; ++s)
#pragma unroll
            for (int j = 0; j < 4; ++j) {
                float os = __shfl_xor(best[s][j], off, 64);
                int   ok = __shfl_xor(bk[s][j],   off, 64);
                bool t = (os > best[s][j]) || (os == best[s][j] && ok < bk[s][j]);
                best[s][j] = t ? os : best[s][j];
                bk[s][j]   = t ? ok : bk[s][j];
            }

    if (row16 == 0) {                     // lanes 0,16,32,48 hold rows kgrp*4..+3
#pragma unroll
        for (int s = 0; s < 4; ++s)
#pragma unroll
            for (int j = 0; j < 4; ++j) {
                int t0 = tile * 256 + wid * 64 + s * 16 + kgrp * 4 + j;
                float d = best[s][j] * -1.1920928955078125e-7f;  // *-2^-23, exact
                unsigned u = __float_as_uint(d);
                u ^= (u & 0x80000000u) ? 0xFFFFFFFFu : 0x80000000u;  // sortable
                unsigned long long key =
                    ((unsigned long long)u << 32) | (unsigned)bk[s][j];
                atomicMin(keys + t0, key);
            }
    }
}

// ---------------------------------------------------------------------------
// Kernel C: decode keys, gather code, write zq (BCHW), loss.
// 128 blocks x 256 threads; 32 tokens/block, 8 channel-quads.
// ---------------------------------------------------------------------------
__global__ __launch_bounds__(256) void vq_finalize(const float* __restrict__ z,
                                                   const float* __restrict__ cb,
                                                   const unsigned long long* __restrict__ keys,
                                                   float* __restrict__ out) {
    const int tok0 = blockIdx.x * 32;
    const int b = tok0 >> 10, hw0 = tok0 & 1023;
    const int tt = threadIdx.x & 31;   // token within tile
    const int sq = threadIdx.x >> 5;   // channel quad 0..7
    const int tok = tok0 + tt;

    const int k  = (int)(keys[tok] & 0xFFFFFFFFu);
    const int c0 = sq * 4;
    float4 e = *(const float4*)(cb + (size_t)k * C_DIM + c0);
    float ev[4] = {e.x, e.y, e.z, e.w};

    const float* zp = z   + (size_t)b * (C_DIM * 1024) + hw0 + tt;
    float*       op = out + (size_t)b * (C_DIM * 1024) + hw0 + tt;
    float lsum = 0.f;
#pragma unroll
    for (int j = 0; j < 4; ++j) {
        float zc = zp[(size_t)(c0 + j) * 1024];
        float df = ev[j] - zc;
        lsum = fmaf(df, df, lsum);
        op[(size_t)(c0 + j) * 1024] = ev[j];
    }

#pragma unroll
    for (int off = 32; off > 0; off >>= 1) lsum += __shfl_down(lsum, off, 64);
    __shared__ float wsum[4];
    const int lane = threadIdx.x & 63, wid = threadIdx.x >> 6;
    if (lane == 0) wsum[wid] = lsum;
    __syncthreads();
    if (threadIdx.x == 0)
        atomicAdd(out + OUT_N, (wsum[0] + wsum[1] + wsum[2] + wsum[3]) * (1.25f / (float)OUT_N));
}

// ---------------------------------------------------------------------------
extern "C" void kernel_launch(void* const* d_in, const int* in_sizes, int n_in,
                              void* d_out, int out_size, void* d_ws, size_t ws_size,
                              hipStream_t stream) {
    const float* z  = (const float*)d_in[0];
    const float* cb = (const float*)d_in[1];
    float* out = (float*)d_out;

    _Float16* zh = (_Float16*)d_ws;                       // 256 KB
    _Float16* zl = zh + (size_t)N_TOK * C_DIM;            // 256 KB
    _Float16* ch = zl + (size_t)N_TOK * C_DIM;            // 2 MB
    _Float16* cl = ch + (size_t)K_CB * C_DIM;             // 2 MB
    float*  norms = (float*)(cl + (size_t)K_CB * C_DIM);  // 128 KB
    unsigned long long* keys = (unsigned long long*)(norms + K_CB); // 32 KB

    hipMemsetAsync(keys, 0xFF, (size_t)N_TOK * 8, stream);   // keys = u64 max
    vq_prep    <<<144, 256, 0, stream>>>(z, cb, zh, zl, ch, cl, norms, out);
    vq_mfma    <<<(N_TOK / 256) * SLICES, 256, 0, stream>>>(zh, zl, ch, cl, norms, keys);
    vq_finalize<<<N_TOK / 32, 256, 0, stream>>>(z, cb, keys, out);
}

// Round 13
// 117.321 us; speedup vs baseline: 1.0371x; 1.0371x over previous
//
#include <hip/hip_runtime.h>
#include <math.h>

#define K_CB    32768
#define C_DIM   32
#define N_TOK   4096
#define OUT_N   (N_TOK * C_DIM)

#define SLICES  64
#define KPERSL  (K_CB / SLICES)    // 512 codes per slice
#define GROUPS  (KPERSL / 16)      // 32 groups of 16 codes
#define SCALE   4096.0f            // 2^12 pre-scale (exact)

typedef _Float16 half8   __attribute__((ext_vector_type(8)));
typedef float    floatx4 __attribute__((ext_vector_type(4)));

// ---------------------------------------------------------------------------
// Kernel A (fused prep): blocks 0..127 codebook -> fp16 hi/lo + norms;
// blocks 128..143 z -> token-major fp16 hi/lo + keys init (replaces memset).
// Zeroes the loss cell (d_out is 0xAA-poisoned every launch).
// ---------------------------------------------------------------------------
__global__ __launch_bounds__(256) void vq_prep(const float* __restrict__ z,
                                               const float* __restrict__ cb,
                                               _Float16* __restrict__ zh,
                                               _Float16* __restrict__ zl,
                                               _Float16* __restrict__ ch,
                                               _Float16* __restrict__ cl,
                                               float* __restrict__ nrm,
                                               unsigned long long* __restrict__ keys,
                                               float* __restrict__ out) {
    const int bb = blockIdx.x;
    if (bb < 128) {                       // ---- codebook part
        const int k = bb * 256 + threadIdx.x;
        const float4* src = (const float4*)(cb + (size_t)k * C_DIM);
        _Float16 h[C_DIM], l[C_DIM];
        float s = 0.f;
#pragma unroll
        for (int i = 0; i < 8; ++i) {
            float4 v = src[i];
            s = fmaf(v.x, v.x, s); s = fmaf(v.y, v.y, s);
            s = fmaf(v.z, v.z, s); s = fmaf(v.w, v.w, s);
            float x[4] = {v.x * SCALE, v.y * SCALE, v.z * SCALE, v.w * SCALE};
#pragma unroll
            for (int j = 0; j < 4; ++j) {
                _Float16 hh = (_Float16)x[j];
                h[i * 4 + j] = hh;
                l[i * 4 + j] = (_Float16)(x[j] - (float)hh);
            }
        }
        nrm[k] = s;
        half8* dh = (half8*)(ch + (size_t)k * C_DIM);
        half8* dl = (half8*)(cl + (size_t)k * C_DIM);
#pragma unroll
        for (int i = 0; i < 4; ++i) {
            dh[i] = *(half8*)&h[i * 8];
            dl[i] = *(half8*)&l[i * 8];
        }
        if (k == 0) out[OUT_N] = 0.f;
    } else {                              // ---- z part
        const int tok = (bb - 128) * 256 + threadIdx.x;
        const int b = tok >> 10, hw = tok & 1023;
        const float* zp = z + (size_t)b * (C_DIM * 1024) + hw;
        _Float16 h[C_DIM], l[C_DIM];
#pragma unroll
        for (int c = 0; c < C_DIM; ++c) {
            float xs = zp[(size_t)c * 1024] * SCALE;   // coalesced across lanes
            _Float16 hh = (_Float16)xs;
            h[c] = hh;
            l[c] = (_Float16)(xs - (float)hh);
        }
        half8* dh = (half8*)(zh + (size_t)tok * C_DIM);
        half8* dl = (half8*)(zl + (size_t)tok * C_DIM);
#pragma unroll
        for (int i = 0; i < 4; ++i) {
            dh[i] = *(half8*)&h[i * 8];
            dl[i] = *(half8*)&l[i * 8];
        }
        keys[tok] = 0xFFFFFFFFFFFFFFFFull;   // atomicMin identity
    }
}

// ---------------------------------------------------------------------------
// Kernel B: MFMA argmin, latency-hiding version.
// Wave = 2 strips x 16 tokens; block = 4 waves = 128 tokens; slice = 512
// codes; grid = 32 tiles x 64 slices = 2048 blocks (32 waves/CU theoretical).
// B fragments software-pipelined one group ahead (hides ~200cy L2 latency —
// R8 replay showed L2-warm == cold dur, i.e. un-prefetched load chains).
// acc = z.e*2^24 - nrm*2^23 via 3 fp16 MFMAs; argmin d == argmax acc.
// Merge via u64 atomicMin key = sortable(d)<<32 | k (min d, tie -> min k).
// ---------------------------------------------------------------------------
__global__ __launch_bounds__(256) void vq_mfma(const _Float16* __restrict__ zh,
                                               const _Float16* __restrict__ zl,
                                               const _Float16* __restrict__ ch,
                                               const _Float16* __restrict__ cl,
                                               const float* __restrict__ nrm,
                                               unsigned long long* __restrict__ keys) {
    const int tid   = threadIdx.x;
    const int lane  = tid & 63, wid = tid >> 6;
    const int row16 = lane & 15, kgrp = lane >> 4;
    const int tile  = blockIdx.x & 31;    // token tile (128 tokens)
    const int slice = blockIdx.x >> 5;    // code slice (512 codes)
    const int tokA  = tile * 128 + wid * 32 + row16;
    const int code0 = slice * KPERSL;

    // A fragments: 2 strips x (hi,lo), resident all kernel
    const half8 a0h = *(const half8*)(zh + (size_t)tokA * C_DIM + kgrp * 8);
    const half8 a0l = *(const half8*)(zl + (size_t)tokA * C_DIM + kgrp * 8);
    const half8 a1h = *(const half8*)(zh + (size_t)(tokA + 16) * C_DIM + kgrp * 8);
    const half8 a1l = *(const half8*)(zl + (size_t)(tokA + 16) * C_DIM + kgrp * 8);

    const _Float16* pbh = ch + (size_t)(code0 + row16) * C_DIM + kgrp * 8;
    const _Float16* pbl = cl + (size_t)(code0 + row16) * C_DIM + kgrp * 8;
    const float*    pn  = nrm + code0 + row16;
    int kc = code0 + row16;

    float best0[4], best1[4]; int bk0[4], bk1[4];
#pragma unroll
    for (int j = 0; j < 4; ++j) {
        best0[j] = -INFINITY; best1[j] = -INFINITY; bk0[j] = 0; bk1[j] = 0;
    }

    // prologue: load group 0
    half8 bh = *(const half8*)pbh;
    half8 bl = *(const half8*)pbl;
    float nv = *pn;

#define VQ_STEP(BH, BL, NV)                                                    \
    {                                                                          \
        float initv = (NV) * -8388608.0f;  /* -nrm/2 * 2^24 */                 \
        floatx4 acc0 = {initv, initv, initv, initv};                           \
        floatx4 acc1 = acc0;                                                   \
        acc0 = __builtin_amdgcn_mfma_f32_16x16x32_f16(a0h, (BL), acc0, 0,0,0); \
        acc1 = __builtin_amdgcn_mfma_f32_16x16x32_f16(a1h, (BL), acc1, 0,0,0); \
        acc0 = __builtin_amdgcn_mfma_f32_16x16x32_f16(a0l, (BH), acc0, 0,0,0); \
        acc1 = __builtin_amdgcn_mfma_f32_16x16x32_f16(a1l, (BH), acc1, 0,0,0); \
        acc0 = __builtin_amdgcn_mfma_f32_16x16x32_f16(a0h, (BH), acc0, 0,0,0); \
        acc1 = __builtin_amdgcn_mfma_f32_16x16x32_f16(a1h, (BH), acc1, 0,0,0); \
        _Pragma("unroll")                                                      \
        for (int j = 0; j < 4; ++j) {  /* strict > keeps lowest k on ties */   \
            float v0 = acc0[j];                                                \
            bool g0 = v0 > best0[j];                                           \
            best0[j] = g0 ? v0 : best0[j];                                     \
            bk0[j]   = g0 ? kc : bk0[j];                                       \
            float v1 = acc1[j];                                                \
            bool g1 = v1 > best1[j];                                           \
            best1[j] = g1 ? v1 : best1[j];                                     \
            bk1[j]   = g1 ? kc : bk1[j];                                       \
        }                                                                      \
    }

    for (int g = 0; g < GROUPS - 1; ++g) {
        pbh += 16 * C_DIM; pbl += 16 * C_DIM; pn += 16;
        half8 nbh = *(const half8*)pbh;    // prefetch g+1 (hidden under MFMAs)
        half8 nbl = *(const half8*)pbl;
        float nnv = *pn;
        VQ_STEP(bh, bl, nv)
        bh = nbh; bl = nbl; nv = nnv; kc += 16;
    }
    VQ_STEP(bh, bl, nv)                    // epilogue group
#undef VQ_STEP

    // reduce across the 16 code columns (low 4 lane bits); (max acc, min k)
#pragma unroll
    for (int off = 1; off < 16; off <<= 1)
#pragma unroll
        for (int j = 0; j < 4; ++j) {
            float os = __shfl_xor(best0[j], off, 64);
            int   ok = __shfl_xor(bk0[j],   off, 64);
            bool t = (os > best0[j]) || (os == best0[j] && ok < bk0[j]);
            best0[j] = t ? os : best0[j];
            bk0[j]   = t ? ok : bk0[j];
            os = __shfl_xor(best1[j], off, 64);
            ok = __shfl_xor(bk1[j],   off, 64);
            t = (os > best1[j]) || (os == best1[j] && ok < bk1[j]);
            best1[j] = t ? os : best1[j];
            bk1[j]   = t ? ok : bk1[j];
        }

    if (row16 == 0) {                      // lanes 0,16,32,48 hold rows kgrp*4..+3
#pragma unroll
        for (int j = 0; j < 4; ++j) {
#pragma unroll
            for (int s = 0; s < 2; ++s) {
                int t0 = tile * 128 + wid * 32 + s * 16 + kgrp * 4 + j;
                float d = (s ? best1[j] : best0[j]) * -1.1920928955078125e-7f; // *-2^-23
                unsigned u = __float_as_uint(d);
                u ^= (u & 0x80000000u) ? 0xFFFFFFFFu : 0x80000000u;  // sortable
                unsigned long long key =
                    ((unsigned long long)u << 32) | (unsigned)(s ? bk1[j] : bk0[j]);
                atomicMin(keys + t0, key);
            }
        }
    }
}

// ---------------------------------------------------------------------------
// Kernel C: decode keys, gather code, write zq (BCHW), loss.
// 128 blocks x 256 threads; 32 tokens/block, 8 channel-quads.
// ---------------------------------------------------------------------------
__global__ __launch_bounds__(256) void vq_finalize(const float* __restrict__ z,
                                                   const float* __restrict__ cb,
                                                   const unsigned long long* __restrict__ keys,
                                                   float* __restrict__ out) {
    const int tok0 = blockIdx.x * 32;
    const int b = tok0 >> 10, hw0 = tok0 & 1023;
    const int tt = threadIdx.x & 31;   // token within tile
    const int sq = threadIdx.x >> 5;   // channel quad 0..7
    const int tok = tok0 + tt;

    const int k  = (int)(keys[tok] & 0xFFFFFFFFu);
    const int c0 = sq * 4;
    float4 e = *(const float4*)(cb + (size_t)k * C_DIM + c0);
    float ev[4] = {e.x, e.y, e.z, e.w};

    const float* zp = z   + (size_t)b * (C_DIM * 1024) + hw0 + tt;
    float*       op = out + (size_t)b * (C_DIM * 1024) + hw0 + tt;
    float lsum = 0.f;
#pragma unroll
    for (int j = 0; j < 4; ++j) {
        float zc = zp[(size_t)(c0 + j) * 1024];
        float df = ev[j] - zc;
        lsum = fmaf(df, df, lsum);
        op[(size_t)(c0 + j) * 1024] = ev[j];
    }

#pragma unroll
    for (int off = 32; off > 0; off >>= 1) lsum += __shfl_down(lsum, off, 64);
    __shared__ float wsum[4];
    const int lane = threadIdx.x & 63, wid = threadIdx.x >> 6;
    if (lane == 0) wsum[wid] = lsum;
    __syncthreads();
    if (threadIdx.x == 0)
        atomicAdd(out + OUT_N, (wsum[0] + wsum[1] + wsum[2] + wsum[3]) * (1.25f / (float)OUT_N));
}

// ---------------------------------------------------------------------------
extern "C" void kernel_launch(void* const* d_in, const int* in_sizes, int n_in,
                              void* d_out, int out_size, void* d_ws, size_t ws_size,
                              hipStream_t stream) {
    const float* z  = (const float*)d_in[0];
    const float* cb = (const float*)d_in[1];
    float* out = (float*)d_out;

    _Float16* zh = (_Float16*)d_ws;                       // 256 KB
    _Float16* zl = zh + (size_t)N_TOK * C_DIM;            // 256 KB
    _Float16* ch = zl + (size_t)N_TOK * C_DIM;            // 2 MB
    _Float16* cl = ch + (size_t)K_CB * C_DIM;             // 2 MB
    float*  norms = (float*)(cl + (size_t)K_CB * C_DIM);  // 128 KB
    unsigned long long* keys = (unsigned long long*)(norms + K_CB); // 32 KB

    vq_prep    <<<144, 256, 0, stream>>>(z, cb, zh, zl, ch, cl, norms, keys, out);
    vq_mfma    <<<(N_TOK / 128) * SLICES, 256, 0, stream>>>(zh, zl, ch, cl, norms, keys);
    vq_finalize<<<N_TOK / 32, 256, 0, stream>>>(z, cb, keys, out);
}